// Round 12
// baseline (1479.431 us; speedup 1.0000x reference)
//
#include <hip/hip_runtime.h>
#include <hip/hip_bf16.h>
#include <math.h>

// Problem constants (SimpleLM): L=6, B=4, T=1024, V=32000, E=768, H=12, D=64
#define L_LAYERS 6
#define BB 4
#define TT 1024
#define VV 32000
#define EE 768
#define HH 12
#define DD 64
#define BT (BB * TT)          // 4096 rows of activations

typedef unsigned short u16;
typedef unsigned int   u32;
typedef __attribute__((ext_vector_type(8))) short short8;
typedef __attribute__((ext_vector_type(8))) unsigned short ushort8v;
typedef __attribute__((ext_vector_type(4))) unsigned short ushort4v;
typedef __attribute__((ext_vector_type(4))) float f32x4;

__device__ __forceinline__ float b2f_lo(u32 u) { union { u32 i; float f; } c; c.i = u << 16;          return c.f; }
__device__ __forceinline__ float b2f_hi(u32 u) { union { u32 i; float f; } c; c.i = u & 0xffff0000u;  return c.f; }
__device__ __forceinline__ u16  f2b(float f)   { union { float f; u32 i; } c{f}; u32 r = c.i + 0x7fffu + ((c.i >> 16) & 1u); return (u16)(r >> 16); }

__device__ __forceinline__ void gload16(const void* g, void* l) {
    __builtin_amdgcn_global_load_lds(
        (const __attribute__((address_space(1))) void*)g,
        (__attribute__((address_space(3))) void*)l, 16, 0, 0);
}

// per-layer bf16 weight block: 4x(768x768) + 3072x768 + 768x3072
#define WT_LAYER 7077888u
#define WT_HEAD_OFF ((size_t)L_LAYERS * WT_LAYER)     // 42,467,328 u16

// ---------------------------------------------------------------------------
// Embedding: x[b,t,e] = tok_emb[idx[b,t], e] + pos_emb[t, e]  (f32 out)
// ---------------------------------------------------------------------------
__global__ __launch_bounds__(256) void embed_kernel(
    const int* __restrict__ idx, const float* __restrict__ tok_emb,
    const float* __restrict__ pos_emb, float* __restrict__ x)
{
    int i = blockIdx.x * 256 + threadIdx.x;          // < BT*EE
    int e  = i % EE;
    int bt = i / EE;
    int t  = bt % TT;
    int tok = idx[bt];
    x[i] = tok_emb[(size_t)tok * EE + e] + pos_emb[(size_t)t * EE + e];
}

// ---------------------------------------------------------------------------
// LayerNorm over E=768, f32 in -> bf16 out. 4 rows/block, one wave per row,
// barrier-free (wave shfl reduction), f32x4 loads, 8B packed stores.
// ---------------------------------------------------------------------------
__global__ __launch_bounds__(256) void ln_kernel(
    const float* __restrict__ X, const float* __restrict__ w,
    const float* __restrict__ b, u16* __restrict__ Y)
{
    const int lane = threadIdx.x & 63;
    const size_t row = blockIdx.x * 4 + (threadIdx.x >> 6);
    const float* x = X + row * EE;

    f32x4 v[3];
    #pragma unroll
    for (int k = 0; k < 3; k++)
        v[k] = *(const f32x4*)&x[lane * 4 + k * 256];

    float s = 0.0f;
    #pragma unroll
    for (int k = 0; k < 3; k++) s += v[k][0] + v[k][1] + v[k][2] + v[k][3];
    #pragma unroll
    for (int off = 32; off; off >>= 1) s += __shfl_xor(s, off);
    const float mean = s * (1.0f / EE);

    float q = 0.0f;
    #pragma unroll
    for (int k = 0; k < 3; k++)
        #pragma unroll
        for (int j = 0; j < 4; j++) {
            v[k][j] -= mean;
            q += v[k][j] * v[k][j];
        }
    #pragma unroll
    for (int off = 32; off; off >>= 1) q += __shfl_xor(q, off);
    const float rstd = rsqrtf(q * (1.0f / EE) + 1e-5f);

    u16* y = Y + row * EE;
    #pragma unroll
    for (int k = 0; k < 3; k++) {
        const f32x4 wv = *(const f32x4*)&w[lane * 4 + k * 256];
        const f32x4 bv = *(const f32x4*)&b[lane * 4 + k * 256];
        ushort4v o;
        #pragma unroll
        for (int j = 0; j < 4; j++) o[j] = f2b(v[k][j] * rstd * wv[j] + bv[j]);
        *(ushort4v*)&y[lane * 4 + k * 256] = o;
    }
}

// ---------------------------------------------------------------------------
// Transpose + convert 32x32 tile core: W f32 [K,N] -> Wt bf16 [N,K]
// ---------------------------------------------------------------------------
__device__ __forceinline__ void transpose_tile(
    const float* __restrict__ W, u16* __restrict__ Wt,
    int K, int N, int kt, int nt)
{
    __shared__ float t[32][33];
    const int k0 = kt * 32;
    const int n0 = nt * 32;
    const int c = threadIdx.x & 31;
    const int r = threadIdx.x >> 5;   // 0..7
    #pragma unroll
    for (int i = 0; i < 4; i++)
        t[r + i * 8][c] = W[(size_t)(k0 + r + i * 8) * N + n0 + c];
    __syncthreads();
    #pragma unroll
    for (int i = 0; i < 4; i++) {
        int rr = r + i * 8;
        Wt[(size_t)(n0 + rr) * K + k0 + c] = f2b(t[c][rr]);
    }
}

// Per-layer 6-matrix transpose core (6912 tiles)
__device__ __forceinline__ void transpose_layer_core(
    const float* wq, const float* wk, const float* wv, const float* wo,
    const float* w1, const float* w2, u16* wt, int t)
{
    if (t < 2304) {                       // 4 x (768x768), 576 tiles each
        const int m = t / 576, r = t % 576;
        const float* Ws[4] = {wq, wk, wv, wo};
        transpose_tile(Ws[m], wt + (size_t)m * 768 * 768, 768, 768, r / 24, r % 24);
    } else if (t < 4608) {                // w1: K=768, N=3072 -> w1T [3072,768]
        const int r = t - 2304;
        transpose_tile(w1, wt + (size_t)4 * 768 * 768, 768, 3072, r / 96, r % 96);
    } else {                              // w2: K=3072, N=768 -> w2T [768,3072]
        const int r = t - 4608;
        transpose_tile(w2, wt + (size_t)4 * 768 * 768 + (size_t)3072 * 768,
                       3072, 768, r / 24, r % 24);
    }
}

// Fallback: single-layer transpose (wt reused per layer; small-ws path)
__global__ __launch_bounds__(256) void transpose_layer(
    const float* __restrict__ wq, const float* __restrict__ wk,
    const float* __restrict__ wv, const float* __restrict__ wo,
    const float* __restrict__ w1, const float* __restrict__ w2,
    u16* __restrict__ wt)
{
    transpose_layer_core(wq, wk, wv, wo, w1, w2, wt, blockIdx.x);
}

// Fallback: single-matrix transpose (head_w)
__global__ __launch_bounds__(256) void transpose_cvt(
    const float* __restrict__ W, u16* __restrict__ Wt, int K, int N)
{
    transpose_tile(W, Wt, K, N, blockIdx.y, blockIdx.x);
}

// Big-ws path: ALL weights (6 layers + head) transposed in ONE dispatch.
// 6*6912 layer tiles + 24000 head tiles = 65472 blocks.
__global__ __launch_bounds__(256) void transpose_all(
    const float* __restrict__ wq, const float* __restrict__ wk,
    const float* __restrict__ wv, const float* __restrict__ wo,
    const float* __restrict__ w1, const float* __restrict__ w2,
    const float* __restrict__ head_w, u16* __restrict__ wt)
{
    const int t = blockIdx.x;
    if (t < L_LAYERS * 6912) {
        const int l = t / 6912, r = t % 6912;
        const size_t oEE = (size_t)l * EE * EE;
        const size_t oEF = (size_t)l * EE * 4 * EE;
        transpose_layer_core(wq + oEE, wk + oEE, wv + oEE, wo + oEE,
                             w1 + oEF, w2 + oEF,
                             wt + (size_t)l * WT_LAYER, r);
    } else {
        const int r = t - L_LAYERS * 6912;       // 0..23999; head 768x32000
        transpose_tile(head_w, wt + WT_HEAD_OFF, 768, 32000, r / 1000, r % 1000);
    }
}

// ---------------------------------------------------------------------------
// bf16 MFMA GEMM (128-wide tiles): C = A @ Bt^T (+bias)(+res)(+relu)
// m97-style 2-barrier loop, r4-proven config (M-fast grid, no xcd swizzle —
// r8: swizzle tripled FETCH; no NT stores — r11: +20% WRITE amplification).
// ---------------------------------------------------------------------------
template<int RELU, int RES, int OUTBF, int MFRAG>
__global__ __launch_bounds__(256) void gemm_bf16(
    const u16* __restrict__ A, const u16* __restrict__ Bt,
    const float* __restrict__ bias, const float* __restrict__ res,
    void* __restrict__ Cv, int M, int N, int K)
{
    constexpr int TM = MFRAG * 32;
    __shared__ u16 As[TM * 64];
    __shared__ u16 Bs[128 * 64];

    const int tid  = threadIdx.x;
    const int lane = tid & 63;
    const int w    = tid >> 6;
    const int wr   = w >> 1, wc = w & 1;
    const int m0 = blockIdx.x * TM;     // M is the fast grid dim
    const int n0 = blockIdx.y * 128;

    const int cs = (lane & 7) ^ (lane >> 3);
    const int rl = lane >> 3;

    int aoff[2 * MFRAG], boff[8];
    const int kq = lane >> 4;
    #pragma unroll
    for (int mi = 0; mi < MFRAG; mi++) {
        int rg = wr * (MFRAG * 16) + mi * 16 + (lane & 15);
        #pragma unroll
        for (int ks = 0; ks < 2; ks++)
            aoff[2 * mi + ks] = rg * 64 + (((ks * 4 + kq) ^ (rg & 7)) * 8);
    }
    #pragma unroll
    for (int ni = 0; ni < 4; ni++) {
        int rg = wc * 64 + ni * 16 + (lane & 15);
        #pragma unroll
        for (int ks = 0; ks < 2; ks++)
            boff[2 * ni + ks] = rg * 64 + (((ks * 4 + kq) ^ (rg & 7)) * 8);
    }

    f32x4 acc[MFRAG][4] = {};

    for (int k0 = 0; k0 < K; k0 += 64) {
        __syncthreads();
        #pragma unroll
        for (int i = 0; i < MFRAG; i++) {
            const int seg = i * 4 + w;
            const int row = seg * 8 + rl;
            gload16(A + (size_t)(m0 + row) * K + k0 + cs * 8, &As[seg * 512]);
        }
        #pragma unroll
        for (int i = 0; i < 4; i++) {
            const int seg = i * 4 + w;
            const int row = seg * 8 + rl;
            gload16(Bt + (size_t)(n0 + row) * K + k0 + cs * 8, &Bs[seg * 512]);
        }
        __syncthreads();
        #pragma unroll
        for (int ks = 0; ks < 2; ks++) {
            short8 af[MFRAG], bfv[4];
            #pragma unroll
            for (int mi = 0; mi < MFRAG; mi++) af[mi] = *(const short8*)&As[aoff[2 * mi + ks]];
            #pragma unroll
            for (int ni = 0; ni < 4; ni++) bfv[ni] = *(const short8*)&Bs[boff[2 * ni + ks]];
            #pragma unroll
            for (int mi = 0; mi < MFRAG; mi++)
                #pragma unroll
                for (int ni = 0; ni < 4; ni++)
                    acc[mi][ni] = __builtin_amdgcn_mfma_f32_16x16x32_bf16(
                        af[mi], bfv[ni], acc[mi][ni], 0, 0, 0);
        }
    }

    const int rbase = m0 + wr * (MFRAG * 16) + (lane >> 4) * 4;
    const int cbase = n0 + wc * 64 + (lane & 15);
    #pragma unroll
    for (int ni = 0; ni < 4; ni++) {
        const int c = cbase + ni * 16;
        const float bv = bias ? bias[c] : 0.0f;
        #pragma unroll
        for (int mi = 0; mi < MFRAG; mi++) {
            const int r = rbase + mi * 16;
            #pragma unroll
            for (int i = 0; i < 4; i++) {
                float v = acc[mi][ni][i] + bv;
                const size_t off = (size_t)(r + i) * N + c;
                if (RES)  v += res[off];
                if (RELU) v = fmaxf(v, 0.0f);
                if (OUTBF) ((u16*)Cv)[off] = f2b(v);
                else       ((float*)Cv)[off] = v;
            }
        }
    }
}

// ---------------------------------------------------------------------------
// MFMA flash attention v5: block per (q-tile 64, h, b), 256 threads = 4 waves.
// SWAPPED QK^T (mfma(K,Q)): scores come out transposed so each lane owns ONE
// q-row (q = lane&15) with its 16 k-scores IN-LANE -> row max/sum need only
// 2 shfl each (was 16); P-writes are contiguous u32 pairs; ones-column MFMA
// for l no longer needed (in-lane sum). K dbuf via global_load_lds + XOR
// swizzle; V->regs during QK^T, LDS after PV. One barrier/tile. Defer-max.
// Cross q-mapping (softmax q=lr vs accumulator q=lk*4+i) resolved by 4 shfl
// on the rare rescale path and once at the epilogue. LDS 43 KB, 3 blocks/CU.
// ---------------------------------------------------------------------------
#define AST 72
__global__ __launch_bounds__(256) void attn_mfma(
    const u16* __restrict__ qkv, u16* __restrict__ O)
{
    const int tid = threadIdx.x;
    const int qi = blockIdx.x;
    const int h  = blockIdx.y;
    const int b  = blockIdx.z;
    const int q0 = qi * 64;

    __shared__ u16 Ks[2][64 * 64];     // swizzled, b128-aligned rows
    __shared__ u16 Vt[2][64 * AST];    // V^T [d][k]
    __shared__ u16 Ps[64 * AST];       // Q staging, then P tile (wave-private rows)

    const int lane = tid & 63;
    const int w    = tid >> 6;
    const int lr   = lane & 15;
    const int lk   = lane >> 4;        // k-quad 0..3

    const int cs = (lane & 7) ^ (lane >> 3);
    const int rl = lane >> 3;
    const int vk2 = tid & 31;          // k-pair index
    const int vdc = tid >> 5;          // d-chunk 0..7

    // ---- stage Q into Ps, hoist fragments (used as the MFMA B-operand) ----
    {
        const int sr = tid >> 2, sc = tid & 3;
        const u16* src = qkv + (size_t)(b * TT + q0 + sr) * 2304 + h * 64 + sc * 16;
        *(ushort8v*)&Ps[sr * AST + sc * 16]     = *(const ushort8v*)src;
        *(ushort8v*)&Ps[sr * AST + sc * 16 + 8] = *(const ushort8v*)(src + 8);
    }
    __syncthreads();
    short8 aq[2];
    #pragma unroll
    for (int ks = 0; ks < 2; ks++)
        aq[ks] = *(const short8*)&Ps[(w * 16 + lr) * AST + lk * 8 + ks * 32];

    ushort8v vr0, vr1;
    auto K_ISSUE = [&](int t, int bf) {
        const int k0 = t * 64;
        #pragma unroll
        for (int j = 0; j < 2; ++j) {
            const int seg = j * 4 + w;
            const int row = seg * 8 + rl;
            gload16(qkv + (size_t)(b * TT + k0 + row) * 2304 + 768 + h * 64 + cs * 8,
                    &Ks[bf][seg * 512]);
        }
    };
    auto V_LOAD = [&](int t) {
        const int k0 = t * 64;
        const u16* p = qkv + (size_t)(b * TT + k0 + 2 * vk2) * 2304 + 1536 + h * 64 + vdc * 8;
        vr0 = *(const ushort8v*)p;
        vr1 = *(const ushort8v*)(p + 2304);
    };
    auto V_WRITE = [&](int bf) {
        #pragma unroll
        for (int j = 0; j < 8; ++j) {
            const u32 val = (u32)vr0[j] | ((u32)vr1[j] << 16);
            *(u32*)&Vt[bf][(vdc * 8 + j) * AST + 2 * vk2] = val;
        }
    };

    K_ISSUE(0, 0);
    V_LOAD(0);
    V_WRITE(0);
    __syncthreads();

    f32x4 oacc[4] = {};                // O: q = w*16 + lk*4 + i, d = dt*16 + lr
    float m_run = -3.0e38f, l_run = 0.0f;   // stats for q = w*16 + lr

    const int qrow = q0 + w * 16 + lr;      // this lane's softmax q-row
    const float SC = 0.18033688f;           // 0.125 * log2(e)

    for (int t = 0; t <= qi; ++t) {
        const int cur = t & 1;

        // ---- QK^T swapped: A = K-frag, B = Q-frag -> S^T[k][q] ----
        f32x4 sfrag[4] = {};
        #pragma unroll
        for (int ks = 0; ks < 2; ks++)
            #pragma unroll
            for (int nt = 0; nt < 4; nt++) {
                const int rg = nt * 16 + lr;
                short8 bk = *(const short8*)&Ks[cur][rg * 64 + (((ks * 4 + lk) ^ (rg & 7)) * 8)];
                sfrag[nt] = __builtin_amdgcn_mfma_f32_16x16x32_bf16(bk, aq[ks], sfrag[nt], 0, 0, 0);
            }

        // ---- prefetch next tile (K -> LDS dbuf, V -> regs) ----
        if (t < qi) { K_ISSUE(t + 1, cur ^ 1); V_LOAD(t + 1); }

        // ---- softmax, log2-domain; lane holds k = nt*16 + lk*4 + i for q=lr ----
        const int k0 = t * 64;
        float sv[4][4];
        float mx = -3.0e38f;
        #pragma unroll
        for (int nt = 0; nt < 4; nt++)
            #pragma unroll
            for (int i = 0; i < 4; i++) {
                float s = sfrag[nt][i] * SC;
                if (t == qi && (k0 + nt * 16 + lk * 4 + i) > qrow) s = -3.0e38f;
                sv[nt][i] = s;
                mx = fmaxf(mx, s);
            }
        mx = fmaxf(mx, __shfl_xor(mx, 16));
        mx = fmaxf(mx, __shfl_xor(mx, 32));

        if (!__all(mx - m_run <= 11.5f)) {      // = 8 nats in log2 units
            const float m_new = fmaxf(m_run, mx);
            const float scale = exp2f(m_run - m_new);
            l_run *= scale;
            float sc_i[4];
            #pragma unroll
            for (int i = 0; i < 4; i++)
                sc_i[i] = __shfl(scale, (lane & 48) | (lk * 4 + i));
            #pragma unroll
            for (int dt = 0; dt < 4; dt++)
                #pragma unroll
                for (int i = 0; i < 4; i++) oacc[dt][i] *= sc_i[i];
            m_run = m_new;
        }

        float rs = 0.0f;
        #pragma unroll
        for (int nt = 0; nt < 4; nt++)
            #pragma unroll
            for (int i = 0; i < 4; i++) {
                const float p = exp2f(sv[nt][i] - m_run);
                sv[nt][i] = p;
                rs += p;
            }
        rs += __shfl_xor(rs, 16);
        rs += __shfl_xor(rs, 32);
        l_run += rs;

        // ---- P (bf16) to LDS: row q = w*16+lr, contiguous u32 pairs ----
        #pragma unroll
        for (int nt = 0; nt < 4; nt++) {
            const u32 p0 = (u32)f2b(sv[nt][0]) | ((u32)f2b(sv[nt][1]) << 16);
            const u32 p1 = (u32)f2b(sv[nt][2]) | ((u32)f2b(sv[nt][3]) << 16);
            u16* dst = &Ps[(w * 16 + lr) * AST + nt * 16 + lk * 4];
            *(u32*)dst       = p0;
            *(u32*)(dst + 2) = p1;
        }

        // ---- PV ----
        #pragma unroll
        for (int ks = 0; ks < 2; ks++) {
            short8 ap = *(const short8*)&Ps[(w * 16 + lr) * AST + lk * 8 + ks * 32];
            #pragma unroll
            for (int dt = 0; dt < 4; dt++) {
                short8 bv = *(const short8*)&Vt[cur][(dt * 16 + lr) * AST + lk * 8 + ks * 32];
                oacc[dt] = __builtin_amdgcn_mfma_f32_16x16x32_bf16(ap, bv, oacc[dt], 0, 0, 0);
            }
        }

        if (t < qi) V_WRITE(cur ^ 1);
        __syncthreads();
    }

    // ---- epilogue: fetch l for q-row lk*4+i from its stats lane ----
    #pragma unroll
    for (int i = 0; i < 4; i++) {
        const float li  = __shfl(l_run, (lane & 48) | (lk * 4 + i));
        const float inv = 1.0f / li;
        u16* dst = O + (size_t)(b * TT + q0 + w * 16 + lk * 4 + i) * 768 + h * 64 + lr;
        #pragma unroll
        for (int dt = 0; dt < 4; dt++)
            dst[dt * 16] = f2b(oacc[dt][i] * inv);
    }
}

// ---------------------------------------------------------------------------
// Host-side launch
// ---------------------------------------------------------------------------
extern "C" void kernel_launch(void* const* d_in, const int* in_sizes, int n_in,
                              void* d_out, int out_size, void* d_ws, size_t ws_size,
                              hipStream_t stream)
{
    (void)in_sizes; (void)n_in; (void)out_size;

    const int*   idx     = (const int*)  d_in[0];
    const float* tok_emb = (const float*)d_in[1];
    const float* pos_emb = (const float*)d_in[2];
    const float* ln1_w   = (const float*)d_in[3];
    const float* ln1_b   = (const float*)d_in[4];
    const float* wq      = (const float*)d_in[5];
    const float* wk      = (const float*)d_in[6];
    const float* wv      = (const float*)d_in[7];
    const float* wo      = (const float*)d_in[8];
    const float* bo      = (const float*)d_in[9];
    const float* ln2_w   = (const float*)d_in[10];
    const float* ln2_b   = (const float*)d_in[11];
    const float* w1      = (const float*)d_in[12];
    const float* b1      = (const float*)d_in[13];
    const float* w2      = (const float*)d_in[14];
    const float* b2      = (const float*)d_in[15];
    const float* lnf_w   = (const float*)d_in[16];
    const float* lnf_b   = (const float*)d_in[17];
    const float* head_w  = (const float*)d_in[18];
    const float* head_b  = (const float*)d_in[19];
    float* out = (float*)d_out;

    // workspace carve
    const size_t S = (size_t)BT * EE;                 // 3,145,728
    float* x   = (float*)d_ws;                        // f32 [BT,768]
    u16*  qkv  = (u16*)(x + S);                       // bf16 [BT,2304]
    u16*  hb   = qkv + (size_t)BT * 2304;             // bf16 [BT,768]
    u16*  ffh  = hb + S;                              // bf16 [BT,3072]
    u16*  wt   = ffh + (size_t)BT * 3072;             // bf16 weights

    // big path needs 62.9 MB activations + 134.1 MB all-layer weights
    const size_t need_big = 62914560u + 134086656u + 1024;
    const bool big = (ws_size >= need_big);

    embed_kernel<<<BT * EE / 256, 256, 0, stream>>>(idx, tok_emb, pos_emb, x);

    if (big)   // all transposes (6 layers + head) in one dispatch
        transpose_all<<<L_LAYERS * 6912 + 24000, 256, 0, stream>>>(
            wq, wk, wv, wo, w1, w2, head_w, wt);

    for (int l = 0; l < L_LAYERS; l++) {
        const size_t oE  = (size_t)l * EE;
        const size_t oEE = (size_t)l * EE * EE;
        const size_t oEF = (size_t)l * EE * 4 * EE;
        u16* wtl = big ? (wt + (size_t)l * WT_LAYER) : wt;

        if (!big)
            transpose_layer<<<6912, 256, 0, stream>>>(
                wq + oEE, wk + oEE, wv + oEE, wo + oEE, w1 + oEF, w2 + oEF, wtl);

        // h = LN1(x)
        ln_kernel<<<BT / 4, 256, 0, stream>>>(x, ln1_w + oE, ln1_b + oE, hb);
        // qkv = h @ [Wq|Wk|Wv]   (bf16 out)
        gemm_bf16<0, 0, 1, 4><<<dim3(BT / 128, 2304 / 128), 256, 0, stream>>>(
            hb, wtl, nullptr, nullptr, qkv, BT, 2304, 768);
        // h = attention(qkv)  — MFMA flash v5 (swapped QK^T)
        attn_mfma<<<dim3(TT / 64, HH, BB), 256, 0, stream>>>(qkv, hb);
        // x = x + h @ Wo + bo   (TM=64: 384 blocks)
        gemm_bf16<0, 1, 0, 2><<<dim3(BT / 64, 768 / 128), 256, 0, stream>>>(
            hb, wtl + (size_t)3 * 768 * 768, bo + oE, x, x, BT, 768, 768);
        // h = LN2(x)
        ln_kernel<<<BT / 4, 256, 0, stream>>>(x, ln2_w + oE, ln2_b + oE, hb);
        // ffh = relu(h @ W1 + b1)  (bf16 out)
        gemm_bf16<1, 0, 1, 4><<<dim3(BT / 128, 3072 / 128), 256, 0, stream>>>(
            hb, wtl + (size_t)4 * 768 * 768, b1 + (size_t)l * 4 * EE, nullptr, ffh, BT, 3072, 768);
        // x = x + ffh @ W2 + b2   (TM=64: 384 blocks)
        gemm_bf16<0, 1, 0, 2><<<dim3(BT / 64, 768 / 128), 256, 0, stream>>>(
            ffh, wtl + (size_t)4 * 768 * 768 + (size_t)3072 * 768, b2 + oE, x, x, BT, 768, 3072);
    }

    // final LN + head
    ln_kernel<<<BT / 4, 256, 0, stream>>>(x, lnf_w, lnf_b, hb);
    u16* wth = big ? (wt + WT_HEAD_OFF) : wt;
    if (!big)
        transpose_cvt<<<dim3(VV / 32, EE / 32), 256, 0, stream>>>(head_w, wth, EE, VV);
    gemm_bf16<0, 0, 0, 4><<<dim3(BT / 128, VV / 128), 256, 0, stream>>>(
        hb, wth, head_b, nullptr, out, BT, VV, 768);
}

// Round 13
// 1453.777 us; speedup vs baseline: 1.0176x; 1.0176x over previous
//
#include <hip/hip_runtime.h>
#include <hip/hip_bf16.h>
#include <math.h>

// Problem constants (SimpleLM): L=6, B=4, T=1024, V=32000, E=768, H=12, D=64
#define L_LAYERS 6
#define BB 4
#define TT 1024
#define VV 32000
#define EE 768
#define HH 12
#define DD 64
#define BT (BB * TT)          // 4096 rows of activations

typedef unsigned short u16;
typedef unsigned int   u32;
typedef __attribute__((ext_vector_type(8))) short short8;
typedef __attribute__((ext_vector_type(8))) unsigned short ushort8v;
typedef __attribute__((ext_vector_type(4))) unsigned short ushort4v;
typedef __attribute__((ext_vector_type(4))) float f32x4;

__device__ __forceinline__ float b2f_lo(u32 u) { union { u32 i; float f; } c; c.i = u << 16;          return c.f; }
__device__ __forceinline__ float b2f_hi(u32 u) { union { u32 i; float f; } c; c.i = u & 0xffff0000u;  return c.f; }
__device__ __forceinline__ u16  f2b(float f)   { union { float f; u32 i; } c{f}; u32 r = c.i + 0x7fffu + ((c.i >> 16) & 1u); return (u16)(r >> 16); }

__device__ __forceinline__ void gload16(const void* g, void* l) {
    __builtin_amdgcn_global_load_lds(
        (const __attribute__((address_space(1))) void*)g,
        (__attribute__((address_space(3))) void*)l, 16, 0, 0);
}

// per-layer bf16 weight block: 4x(768x768) + 3072x768 + 768x3072
#define WT_LAYER 7077888u
#define WT_HEAD_OFF ((size_t)L_LAYERS * WT_LAYER)     // 42,467,328 u16

// ---------------------------------------------------------------------------
// Embedding: x[b,t,e] = tok_emb[idx[b,t], e] + pos_emb[t, e]  (f32 out)
// ---------------------------------------------------------------------------
__global__ __launch_bounds__(256) void embed_kernel(
    const int* __restrict__ idx, const float* __restrict__ tok_emb,
    const float* __restrict__ pos_emb, float* __restrict__ x)
{
    int i = blockIdx.x * 256 + threadIdx.x;          // < BT*EE
    int e  = i % EE;
    int bt = i / EE;
    int t  = bt % TT;
    int tok = idx[bt];
    x[i] = tok_emb[(size_t)tok * EE + e] + pos_emb[(size_t)t * EE + e];
}

// ---------------------------------------------------------------------------
// LayerNorm over E=768, f32 in -> bf16 out. 4 rows/block, one wave per row,
// barrier-free (wave shfl reduction), f32x4 loads, 8B packed stores.
// ---------------------------------------------------------------------------
__global__ __launch_bounds__(256) void ln_kernel(
    const float* __restrict__ X, const float* __restrict__ w,
    const float* __restrict__ b, u16* __restrict__ Y)
{
    const int lane = threadIdx.x & 63;
    const size_t row = blockIdx.x * 4 + (threadIdx.x >> 6);
    const float* x = X + row * EE;

    f32x4 v[3];
    #pragma unroll
    for (int k = 0; k < 3; k++)
        v[k] = *(const f32x4*)&x[lane * 4 + k * 256];

    float s = 0.0f;
    #pragma unroll
    for (int k = 0; k < 3; k++) s += v[k][0] + v[k][1] + v[k][2] + v[k][3];
    #pragma unroll
    for (int off = 32; off; off >>= 1) s += __shfl_xor(s, off);
    const float mean = s * (1.0f / EE);

    float q = 0.0f;
    #pragma unroll
    for (int k = 0; k < 3; k++)
        #pragma unroll
        for (int j = 0; j < 4; j++) {
            v[k][j] -= mean;
            q += v[k][j] * v[k][j];
        }
    #pragma unroll
    for (int off = 32; off; off >>= 1) q += __shfl_xor(q, off);
    const float rstd = rsqrtf(q * (1.0f / EE) + 1e-5f);

    u16* y = Y + row * EE;
    #pragma unroll
    for (int k = 0; k < 3; k++) {
        const f32x4 wv = *(const f32x4*)&w[lane * 4 + k * 256];
        const f32x4 bv = *(const f32x4*)&b[lane * 4 + k * 256];
        ushort4v o;
        #pragma unroll
        for (int j = 0; j < 4; j++) o[j] = f2b(v[k][j] * rstd * wv[j] + bv[j]);
        *(ushort4v*)&y[lane * 4 + k * 256] = o;
    }
}

// ---------------------------------------------------------------------------
// Transpose + convert 32x32 tile core: W f32 [K,N] -> Wt bf16 [N,K]
// ---------------------------------------------------------------------------
__device__ __forceinline__ void transpose_tile(
    const float* __restrict__ W, u16* __restrict__ Wt,
    int K, int N, int kt, int nt)
{
    __shared__ float t[32][33];
    const int k0 = kt * 32;
    const int n0 = nt * 32;
    const int c = threadIdx.x & 31;
    const int r = threadIdx.x >> 5;   // 0..7
    #pragma unroll
    for (int i = 0; i < 4; i++)
        t[r + i * 8][c] = W[(size_t)(k0 + r + i * 8) * N + n0 + c];
    __syncthreads();
    #pragma unroll
    for (int i = 0; i < 4; i++) {
        int rr = r + i * 8;
        Wt[(size_t)(n0 + rr) * K + k0 + c] = f2b(t[c][rr]);
    }
}

// Per-layer 6-matrix transpose core (6912 tiles)
__device__ __forceinline__ void transpose_layer_core(
    const float* wq, const float* wk, const float* wv, const float* wo,
    const float* w1, const float* w2, u16* wt, int t)
{
    if (t < 2304) {                       // 4 x (768x768), 576 tiles each
        const int m = t / 576, r = t % 576;
        const float* Ws[4] = {wq, wk, wv, wo};
        transpose_tile(Ws[m], wt + (size_t)m * 768 * 768, 768, 768, r / 24, r % 24);
    } else if (t < 4608) {                // w1: K=768, N=3072 -> w1T [3072,768]
        const int r = t - 2304;
        transpose_tile(w1, wt + (size_t)4 * 768 * 768, 768, 3072, r / 96, r % 96);
    } else {                              // w2: K=3072, N=768 -> w2T [768,3072]
        const int r = t - 4608;
        transpose_tile(w2, wt + (size_t)4 * 768 * 768 + (size_t)3072 * 768,
                       3072, 768, r / 24, r % 24);
    }
}

// Fallback: single-layer transpose (wt reused per layer; small-ws path)
__global__ __launch_bounds__(256) void transpose_layer(
    const float* __restrict__ wq, const float* __restrict__ wk,
    const float* __restrict__ wv, const float* __restrict__ wo,
    const float* __restrict__ w1, const float* __restrict__ w2,
    u16* __restrict__ wt)
{
    transpose_layer_core(wq, wk, wv, wo, w1, w2, wt, blockIdx.x);
}

// Single-matrix transpose (head_w — launched just-in-time before the head
// GEMM so the bf16 B-panel is L3-warm; r12 showed early transpose costs ~15us)
__global__ __launch_bounds__(256) void transpose_cvt(
    const float* __restrict__ W, u16* __restrict__ Wt, int K, int N)
{
    transpose_tile(W, Wt, K, N, blockIdx.y, blockIdx.x);
}

// Big-ws path: 6 layers' weights transposed in ONE dispatch (41472 blocks).
__global__ __launch_bounds__(256) void transpose_all(
    const float* __restrict__ wq, const float* __restrict__ wk,
    const float* __restrict__ wv, const float* __restrict__ wo,
    const float* __restrict__ w1, const float* __restrict__ w2,
    u16* __restrict__ wt)
{
    const int t = blockIdx.x;
    const int l = t / 6912, r = t % 6912;
    const size_t oEE = (size_t)l * EE * EE;
    const size_t oEF = (size_t)l * EE * 4 * EE;
    transpose_layer_core(wq + oEE, wk + oEE, wv + oEE, wo + oEE,
                         w1 + oEF, w2 + oEF,
                         wt + (size_t)l * WT_LAYER, r);
}

// ---------------------------------------------------------------------------
// bf16 MFMA GEMM (128-wide tiles): C = A @ Bt^T (+bias)(+res)(+relu)
// m97-style 2-barrier loop, r4-proven config (M-fast grid; no xcd swizzle —
// r8: 3x FETCH; no NT stores — r11: +20% WRITE; no LDS repack — r7: conflicts).
// ---------------------------------------------------------------------------
template<int RELU, int RES, int OUTBF, int MFRAG>
__global__ __launch_bounds__(256) void gemm_bf16(
    const u16* __restrict__ A, const u16* __restrict__ Bt,
    const float* __restrict__ bias, const float* __restrict__ res,
    void* __restrict__ Cv, int M, int N, int K)
{
    constexpr int TM = MFRAG * 32;
    __shared__ u16 As[TM * 64];
    __shared__ u16 Bs[128 * 64];

    const int tid  = threadIdx.x;
    const int lane = tid & 63;
    const int w    = tid >> 6;
    const int wr   = w >> 1, wc = w & 1;
    const int m0 = blockIdx.x * TM;     // M is the fast grid dim
    const int n0 = blockIdx.y * 128;

    const int cs = (lane & 7) ^ (lane >> 3);
    const int rl = lane >> 3;

    int aoff[2 * MFRAG], boff[8];
    const int kq = lane >> 4;
    #pragma unroll
    for (int mi = 0; mi < MFRAG; mi++) {
        int rg = wr * (MFRAG * 16) + mi * 16 + (lane & 15);
        #pragma unroll
        for (int ks = 0; ks < 2; ks++)
            aoff[2 * mi + ks] = rg * 64 + (((ks * 4 + kq) ^ (rg & 7)) * 8);
    }
    #pragma unroll
    for (int ni = 0; ni < 4; ni++) {
        int rg = wc * 64 + ni * 16 + (lane & 15);
        #pragma unroll
        for (int ks = 0; ks < 2; ks++)
            boff[2 * ni + ks] = rg * 64 + (((ks * 4 + kq) ^ (rg & 7)) * 8);
    }

    f32x4 acc[MFRAG][4] = {};

    for (int k0 = 0; k0 < K; k0 += 64) {
        __syncthreads();
        #pragma unroll
        for (int i = 0; i < MFRAG; i++) {
            const int seg = i * 4 + w;
            const int row = seg * 8 + rl;
            gload16(A + (size_t)(m0 + row) * K + k0 + cs * 8, &As[seg * 512]);
        }
        #pragma unroll
        for (int i = 0; i < 4; i++) {
            const int seg = i * 4 + w;
            const int row = seg * 8 + rl;
            gload16(Bt + (size_t)(n0 + row) * K + k0 + cs * 8, &Bs[seg * 512]);
        }
        __syncthreads();
        #pragma unroll
        for (int ks = 0; ks < 2; ks++) {
            short8 af[MFRAG], bfv[4];
            #pragma unroll
            for (int mi = 0; mi < MFRAG; mi++) af[mi] = *(const short8*)&As[aoff[2 * mi + ks]];
            #pragma unroll
            for (int ni = 0; ni < 4; ni++) bfv[ni] = *(const short8*)&Bs[boff[2 * ni + ks]];
            #pragma unroll
            for (int mi = 0; mi < MFRAG; mi++)
                #pragma unroll
                for (int ni = 0; ni < 4; ni++)
                    acc[mi][ni] = __builtin_amdgcn_mfma_f32_16x16x32_bf16(
                        af[mi], bfv[ni], acc[mi][ni], 0, 0, 0);
        }
    }

    const int rbase = m0 + wr * (MFRAG * 16) + (lane >> 4) * 4;
    const int cbase = n0 + wc * 64 + (lane & 15);
    #pragma unroll
    for (int ni = 0; ni < 4; ni++) {
        const int c = cbase + ni * 16;
        const float bv = bias ? bias[c] : 0.0f;
        #pragma unroll
        for (int mi = 0; mi < MFRAG; mi++) {
            const int r = rbase + mi * 16;
            #pragma unroll
            for (int i = 0; i < 4; i++) {
                float v = acc[mi][ni][i] + bv;
                const size_t off = (size_t)(r + i) * N + c;
                if (RES)  v += res[off];
                if (RELU) v = fmaxf(v, 0.0f);
                if (OUTBF) ((u16*)Cv)[off] = f2b(v);
                else       ((float*)Cv)[off] = v;
            }
        }
    }
}

// ---------------------------------------------------------------------------
// MFMA flash attention v4 (measured best, r10/r11): block per (q-tile 64, h,
// b), 256 threads = 4 waves. K dbuf via global_load_lds + XOR swizzle;
// V->regs during QK^T, LDS-written after PV. One barrier/tile. Defer-max +
// exp2. l computed by PV MFMA via ones-column in V^T rows 64..79.
// (v5 swapped-QK^T regressed +55us — serial in-lane reduce chains, r12.)
// ---------------------------------------------------------------------------
#define AST 72
__global__ __launch_bounds__(256) void attn_mfma(
    const u16* __restrict__ qkv, u16* __restrict__ O)
{
    const int tid = threadIdx.x;
    const int qi = blockIdx.x;
    const int h  = blockIdx.y;
    const int b  = blockIdx.z;
    const int q0 = qi * 64;

    __shared__ u16 Ks[2][64 * 64];     // swizzled, b128-aligned rows
    __shared__ u16 Vt[2][80 * AST];    // V^T [d][k]; rows 64..79 = ones/zeros
    __shared__ u16 Ps[64 * AST];       // Q staging, then P tile (wave-private rows)

    const int lane = tid & 63;
    const int w    = tid >> 6;
    const int lr   = lane & 15;
    const int lk   = lane >> 4;        // k-group 0..3

    const int cs = (lane & 7) ^ (lane >> 3);
    const int rl = lane >> 3;
    const int vk2 = tid & 31;          // k-pair index
    const int vdc = tid >> 5;          // d-chunk 0..7

    // ---- init ones/zero rows of Vt (once) ----
    for (int i = tid; i < 16 * AST; i += 256) {
        const int r = i / AST, c = i % AST;
        const u16 v = (r == 0) ? (u16)0x3F80 : (u16)0;   // bf16 1.0
        Vt[0][(64 + r) * AST + c] = v;
        Vt[1][(64 + r) * AST + c] = v;
    }

    // ---- stage Q into Ps, hoist A-fragments ----
    {
        const int sr = tid >> 2, sc = tid & 3;
        const u16* src = qkv + (size_t)(b * TT + q0 + sr) * 2304 + h * 64 + sc * 16;
        *(ushort8v*)&Ps[sr * AST + sc * 16]     = *(const ushort8v*)src;
        *(ushort8v*)&Ps[sr * AST + sc * 16 + 8] = *(const ushort8v*)(src + 8);
    }
    __syncthreads();
    short8 aq[2];
    #pragma unroll
    for (int ks = 0; ks < 2; ks++)
        aq[ks] = *(const short8*)&Ps[(w * 16 + lr) * AST + lk * 8 + ks * 32];

    ushort8v vr0, vr1;
    auto K_ISSUE = [&](int t, int bf) {
        const int k0 = t * 64;
        #pragma unroll
        for (int j = 0; j < 2; ++j) {
            const int seg = j * 4 + w;
            const int row = seg * 8 + rl;
            gload16(qkv + (size_t)(b * TT + k0 + row) * 2304 + 768 + h * 64 + cs * 8,
                    &Ks[bf][seg * 512]);
        }
    };
    auto V_LOAD = [&](int t) {
        const int k0 = t * 64;
        const u16* p = qkv + (size_t)(b * TT + k0 + 2 * vk2) * 2304 + 1536 + h * 64 + vdc * 8;
        vr0 = *(const ushort8v*)p;
        vr1 = *(const ushort8v*)(p + 2304);
    };
    auto V_WRITE = [&](int bf) {
        #pragma unroll
        for (int j = 0; j < 8; ++j) {
            const u32 val = (u32)vr0[j] | ((u32)vr1[j] << 16);
            *(u32*)&Vt[bf][(vdc * 8 + j) * AST + 2 * vk2] = val;
        }
    };

    K_ISSUE(0, 0);
    V_LOAD(0);
    V_WRITE(0);
    __syncthreads();

    f32x4 oacc[5] = {};                // [0..3] = O d-tiles, [4] = l (ones col)
    float m_run[4];
    #pragma unroll
    for (int i = 0; i < 4; i++) m_run[i] = -3.0e38f;

    const int qrow = q0 + w * 16 + lk * 4;
    const float SC = 0.18033688f;       // 0.125 * log2(e): scores in log2 domain

    for (int t = 0; t <= qi; ++t) {
        const int cur = t & 1;

        // ---- QK^T ----
        f32x4 sfrag[4] = {};
        #pragma unroll
        for (int ks = 0; ks < 2; ks++)
            #pragma unroll
            for (int nt = 0; nt < 4; nt++) {
                const int rg = nt * 16 + lr;
                short8 bk = *(const short8*)&Ks[cur][rg * 64 + (((ks * 4 + lk) ^ (rg & 7)) * 8)];
                sfrag[nt] = __builtin_amdgcn_mfma_f32_16x16x32_bf16(aq[ks], bk, sfrag[nt], 0, 0, 0);
            }

        // ---- prefetch next tile (K -> LDS dbuf, V -> regs) ----
        if (t < qi) { K_ISSUE(t + 1, cur ^ 1); V_LOAD(t + 1); }

        // ---- softmax in log2 domain (defer-max; l via MFMA ones-column) ----
        const int k0 = t * 64;
        float sv[4][4], mxv[4];
        float need = 0.0f;
        #pragma unroll
        for (int i = 0; i < 4; i++) {
            float mx = -3.0e38f;
            #pragma unroll
            for (int nt = 0; nt < 4; nt++) {
                float s = sfrag[nt][i] * SC;
                if (t == qi && (k0 + nt * 16 + lr) > (qrow + i)) s = -3.0e38f;
                sv[i][nt] = s;
                mx = fmaxf(mx, s);
            }
            mx = fmaxf(mx, __shfl_xor(mx, 1));
            mx = fmaxf(mx, __shfl_xor(mx, 2));
            mx = fmaxf(mx, __shfl_xor(mx, 4));
            mx = fmaxf(mx, __shfl_xor(mx, 8));
            mxv[i] = mx;
            need = fmaxf(need, mx - m_run[i]);
        }
        if (!__all(need <= 11.5f)) {       // = 8 nats in log2 units
            #pragma unroll
            for (int i = 0; i < 4; i++) {
                const float m_new = fmaxf(m_run[i], mxv[i]);
                const float scale = exp2f(m_run[i] - m_new);
                #pragma unroll
                for (int dt = 0; dt < 5; dt++) oacc[dt][i] *= scale;
                m_run[i] = m_new;
            }
        }
        #pragma unroll
        for (int i = 0; i < 4; i++)
            #pragma unroll
            for (int nt = 0; nt < 4; nt++)
                sv[i][nt] = exp2f(sv[i][nt] - m_run[i]);

        // ---- P (bf16) to LDS — wave-private rows, no barrier needed ----
        #pragma unroll
        for (int i = 0; i < 4; i++)
            #pragma unroll
            for (int nt = 0; nt < 4; nt++)
                Ps[(w * 16 + lk * 4 + i) * AST + nt * 16 + lr] = f2b(sv[i][nt]);

        // ---- PV (+ l via dt=4 ones-column) ----
        #pragma unroll
        for (int ks = 0; ks < 2; ks++) {
            short8 ap = *(const short8*)&Ps[(w * 16 + lr) * AST + lk * 8 + ks * 32];
            #pragma unroll
            for (int dt = 0; dt < 5; dt++) {
                short8 bv = *(const short8*)&Vt[cur][(dt * 16 + lr) * AST + lk * 8 + ks * 32];
                oacc[dt] = __builtin_amdgcn_mfma_f32_16x16x32_bf16(ap, bv, oacc[dt], 0, 0, 0);
            }
        }

        if (t < qi) V_WRITE(cur ^ 1);
        __syncthreads();
    }

    // ---- epilogue: l lives in lanes lr==0 of oacc[4]; broadcast per group ----
    #pragma unroll
    for (int i = 0; i < 4; i++) {
        const float li  = __shfl(oacc[4][i], lane & 48);
        const float inv = 1.0f / li;
        u16* dst = O + (size_t)(b * TT + q0 + w * 16 + lk * 4 + i) * 768 + h * 64 + lr;
        #pragma unroll
        for (int dt = 0; dt < 4; dt++)
            dst[dt * 16] = f2b(oacc[dt][i] * inv);
    }
}

// ---------------------------------------------------------------------------
// Host-side launch
// ---------------------------------------------------------------------------
extern "C" void kernel_launch(void* const* d_in, const int* in_sizes, int n_in,
                              void* d_out, int out_size, void* d_ws, size_t ws_size,
                              hipStream_t stream)
{
    (void)in_sizes; (void)n_in; (void)out_size;

    const int*   idx     = (const int*)  d_in[0];
    const float* tok_emb = (const float*)d_in[1];
    const float* pos_emb = (const float*)d_in[2];
    const float* ln1_w   = (const float*)d_in[3];
    const float* ln1_b   = (const float*)d_in[4];
    const float* wq      = (const float*)d_in[5];
    const float* wk      = (const float*)d_in[6];
    const float* wv      = (const float*)d_in[7];
    const float* wo      = (const float*)d_in[8];
    const float* bo      = (const float*)d_in[9];
    const float* ln2_w   = (const float*)d_in[10];
    const float* ln2_b   = (const float*)d_in[11];
    const float* w1      = (const float*)d_in[12];
    const float* b1      = (const float*)d_in[13];
    const float* w2      = (const float*)d_in[14];
    const float* b2      = (const float*)d_in[15];
    const float* lnf_w   = (const float*)d_in[16];
    const float* lnf_b   = (const float*)d_in[17];
    const float* head_w  = (const float*)d_in[18];
    const float* head_b  = (const float*)d_in[19];
    float* out = (float*)d_out;

    // workspace carve
    const size_t S = (size_t)BT * EE;                 // 3,145,728
    float* x   = (float*)d_ws;                        // f32 [BT,768]
    u16*  qkv  = (u16*)(x + S);                       // bf16 [BT,2304]
    u16*  hb   = qkv + (size_t)BT * 2304;             // bf16 [BT,768]
    u16*  ffh  = hb + S;                              // bf16 [BT,3072]
    u16*  wt   = ffh + (size_t)BT * 3072;             // bf16 weights

    // big path: 62.9 MB activations + 134.1 MB all-layer+head weights
    const size_t need_big = 62914560u + 134086656u + 1024;
    const bool big = (ws_size >= need_big);

    embed_kernel<<<BT * EE / 256, 256, 0, stream>>>(idx, tok_emb, pos_emb, x);

    if (big)   // 6 layers' transposes in one dispatch (head done JIT below)
        transpose_all<<<L_LAYERS * 6912, 256, 0, stream>>>(
            wq, wk, wv, wo, w1, w2, wt);

    for (int l = 0; l < L_LAYERS; l++) {
        const size_t oE  = (size_t)l * EE;
        const size_t oEE = (size_t)l * EE * EE;
        const size_t oEF = (size_t)l * EE * 4 * EE;
        u16* wtl = big ? (wt + (size_t)l * WT_LAYER) : wt;

        if (!big)
            transpose_layer<<<6912, 256, 0, stream>>>(
                wq + oEE, wk + oEE, wv + oEE, wo + oEE, w1 + oEF, w2 + oEF, wtl);

        // h = LN1(x)
        ln_kernel<<<BT / 4, 256, 0, stream>>>(x, ln1_w + oE, ln1_b + oE, hb);
        // qkv = h @ [Wq|Wk|Wv]   (bf16 out)
        gemm_bf16<0, 0, 1, 4><<<dim3(BT / 128, 2304 / 128), 256, 0, stream>>>(
            hb, wtl, nullptr, nullptr, qkv, BT, 2304, 768);
        // h = attention(qkv)  — MFMA flash v4
        attn_mfma<<<dim3(TT / 64, HH, BB), 256, 0, stream>>>(qkv, hb);
        // x = x + h @ Wo + bo   (TM=64: 384 blocks)
        gemm_bf16<0, 1, 0, 2><<<dim3(BT / 64, 768 / 128), 256, 0, stream>>>(
            hb, wtl + (size_t)3 * 768 * 768, bo + oE, x, x, BT, 768, 768);
        // h = LN2(x)
        ln_kernel<<<BT / 4, 256, 0, stream>>>(x, ln2_w + oE, ln2_b + oE, hb);
        // ffh = relu(h @ W1 + b1)  (bf16 out)
        gemm_bf16<1, 0, 1, 4><<<dim3(BT / 128, 3072 / 128), 256, 0, stream>>>(
            hb, wtl + (size_t)4 * 768 * 768, b1 + (size_t)l * 4 * EE, nullptr, ffh, BT, 3072, 768);
        // x = x + ffh @ W2 + b2   (TM=64: 384 blocks)
        gemm_bf16<0, 1, 0, 2><<<dim3(BT / 64, 768 / 128), 256, 0, stream>>>(
            ffh, wtl + (size_t)4 * 768 * 768 + (size_t)3072 * 768, b2 + oE, x, x, BT, 768, 3072);
    }

    // final LN + head (head transpose just-in-time: warm B-panel in L3)
    ln_kernel<<<BT / 4, 256, 0, stream>>>(x, lnf_w, lnf_b, hb);
    u16* wth = big ? (wt + WT_HEAD_OFF) : wt;
    transpose_cvt<<<dim3(VV / 32, EE / 32), 256, 0, stream>>>(head_w, wth, EE, VV);
    gemm_bf16<0, 0, 0, 4><<<dim3(BT / 128, VV / 128), 256, 0, stream>>>(
        hb, wth, head_b, nullptr, out, BT, VV, 768);
}

// Round 14
// 1414.574 us; speedup vs baseline: 1.0458x; 1.0277x over previous
//
#include <hip/hip_runtime.h>
#include <hip/hip_bf16.h>
#include <math.h>

// Problem constants (SimpleLM): L=6, B=4, T=1024, V=32000, E=768, H=12, D=64
#define L_LAYERS 6
#define BB 4
#define TT 1024
#define VV 32000
#define EE 768
#define HH 12
#define DD 64
#define BT (BB * TT)          // 4096 rows of activations

typedef unsigned short u16;
typedef unsigned int   u32;
typedef __attribute__((ext_vector_type(8))) short short8;
typedef __attribute__((ext_vector_type(8))) unsigned short ushort8v;
typedef __attribute__((ext_vector_type(4))) unsigned short ushort4v;
typedef __attribute__((ext_vector_type(4))) float f32x4;

__device__ __forceinline__ float b2f_lo(u32 u) { union { u32 i; float f; } c; c.i = u << 16;          return c.f; }
__device__ __forceinline__ float b2f_hi(u32 u) { union { u32 i; float f; } c; c.i = u & 0xffff0000u;  return c.f; }
__device__ __forceinline__ u16  f2b(float f)   { union { float f; u32 i; } c{f}; u32 r = c.i + 0x7fffu + ((c.i >> 16) & 1u); return (u16)(r >> 16); }

__device__ __forceinline__ void gload16(const void* g, void* l) {
    __builtin_amdgcn_global_load_lds(
        (const __attribute__((address_space(1))) void*)g,
        (__attribute__((address_space(3))) void*)l, 16, 0, 0);
}

// per-layer bf16 weight block: 4x(768x768) + 3072x768 + 768x3072
#define WT_LAYER 7077888u
#define WT_HEAD_OFF ((size_t)L_LAYERS * WT_LAYER)     // 42,467,328 u16

// ---------------------------------------------------------------------------
// Embedding: x[b,t,e] = tok_emb[idx[b,t], e] + pos_emb[t, e]  (f32 out)
// ---------------------------------------------------------------------------
__global__ __launch_bounds__(256) void embed_kernel(
    const int* __restrict__ idx, const float* __restrict__ tok_emb,
    const float* __restrict__ pos_emb, float* __restrict__ x)
{
    int i = blockIdx.x * 256 + threadIdx.x;          // < BT*EE
    int e  = i % EE;
    int bt = i / EE;
    int t  = bt % TT;
    int tok = idx[bt];
    x[i] = tok_emb[(size_t)tok * EE + e] + pos_emb[(size_t)t * EE + e];
}

// ---------------------------------------------------------------------------
// LayerNorm over E=768, f32 in -> bf16 out. 4 rows/block, one wave per row,
// barrier-free (wave shfl reduction), f32x4 loads, 8B packed stores.
// ---------------------------------------------------------------------------
__global__ __launch_bounds__(256) void ln_kernel(
    const float* __restrict__ X, const float* __restrict__ w,
    const float* __restrict__ b, u16* __restrict__ Y)
{
    const int lane = threadIdx.x & 63;
    const size_t row = blockIdx.x * 4 + (threadIdx.x >> 6);
    const float* x = X + row * EE;

    f32x4 v[3];
    #pragma unroll
    for (int k = 0; k < 3; k++)
        v[k] = *(const f32x4*)&x[lane * 4 + k * 256];

    float s = 0.0f;
    #pragma unroll
    for (int k = 0; k < 3; k++) s += v[k][0] + v[k][1] + v[k][2] + v[k][3];
    #pragma unroll
    for (int off = 32; off; off >>= 1) s += __shfl_xor(s, off);
    const float mean = s * (1.0f / EE);

    float q = 0.0f;
    #pragma unroll
    for (int k = 0; k < 3; k++)
        #pragma unroll
        for (int j = 0; j < 4; j++) {
            v[k][j] -= mean;
            q += v[k][j] * v[k][j];
        }
    #pragma unroll
    for (int off = 32; off; off >>= 1) q += __shfl_xor(q, off);
    const float rstd = rsqrtf(q * (1.0f / EE) + 1e-5f);

    u16* y = Y + row * EE;
    #pragma unroll
    for (int k = 0; k < 3; k++) {
        const f32x4 wv = *(const f32x4*)&w[lane * 4 + k * 256];
        const f32x4 bv = *(const f32x4*)&b[lane * 4 + k * 256];
        ushort4v o;
        #pragma unroll
        for (int j = 0; j < 4; j++) o[j] = f2b(v[k][j] * rstd * wv[j] + bv[j]);
        *(ushort4v*)&y[lane * 4 + k * 256] = o;
    }
}

// ---------------------------------------------------------------------------
// Transpose + convert 32x32 tile core: W f32 [K,N] -> Wt bf16 [N,K]
// ---------------------------------------------------------------------------
__device__ __forceinline__ void transpose_tile(
    const float* __restrict__ W, u16* __restrict__ Wt,
    int K, int N, int kt, int nt)
{
    __shared__ float t[32][33];
    const int k0 = kt * 32;
    const int n0 = nt * 32;
    const int c = threadIdx.x & 31;
    const int r = threadIdx.x >> 5;   // 0..7
    #pragma unroll
    for (int i = 0; i < 4; i++)
        t[r + i * 8][c] = W[(size_t)(k0 + r + i * 8) * N + n0 + c];
    __syncthreads();
    #pragma unroll
    for (int i = 0; i < 4; i++) {
        int rr = r + i * 8;
        Wt[(size_t)(n0 + rr) * K + k0 + c] = f2b(t[c][rr]);
    }
}

// Per-layer 6-matrix transpose core (6912 tiles)
__device__ __forceinline__ void transpose_layer_core(
    const float* wq, const float* wk, const float* wv, const float* wo,
    const float* w1, const float* w2, u16* wt, int t)
{
    if (t < 2304) {                       // 4 x (768x768), 576 tiles each
        const int m = t / 576, r = t % 576;
        const float* Ws[4] = {wq, wk, wv, wo};
        transpose_tile(Ws[m], wt + (size_t)m * 768 * 768, 768, 768, r / 24, r % 24);
    } else if (t < 4608) {                // w1: K=768, N=3072 -> w1T [3072,768]
        const int r = t - 2304;
        transpose_tile(w1, wt + (size_t)4 * 768 * 768, 768, 3072, r / 96, r % 96);
    } else {                              // w2: K=3072, N=768 -> w2T [768,3072]
        const int r = t - 4608;
        transpose_tile(w2, wt + (size_t)4 * 768 * 768 + (size_t)3072 * 768,
                       3072, 768, r / 24, r % 24);
    }
}

// Fallback: single-layer transpose (wt reused per layer; small-ws path)
__global__ __launch_bounds__(256) void transpose_layer(
    const float* __restrict__ wq, const float* __restrict__ wk,
    const float* __restrict__ wv, const float* __restrict__ wo,
    const float* __restrict__ w1, const float* __restrict__ w2,
    u16* __restrict__ wt)
{
    transpose_layer_core(wq, wk, wv, wo, w1, w2, wt, blockIdx.x);
}

// Fallback: single-matrix transpose (head_w)
__global__ __launch_bounds__(256) void transpose_cvt(
    const float* __restrict__ W, u16* __restrict__ Wt, int K, int N)
{
    transpose_tile(W, Wt, K, N, blockIdx.y, blockIdx.x);
}

// Big-ws path: ALL weights (6 layers + head) transposed in ONE dispatch.
// 6*6912 layer tiles + 24000 head tiles = 65472 blocks.
__global__ __launch_bounds__(256) void transpose_all(
    const float* __restrict__ wq, const float* __restrict__ wk,
    const float* __restrict__ wv, const float* __restrict__ wo,
    const float* __restrict__ w1, const float* __restrict__ w2,
    const float* __restrict__ head_w, u16* __restrict__ wt)
{
    const int t = blockIdx.x;
    if (t < L_LAYERS * 6912) {
        const int l = t / 6912, r = t % 6912;
        const size_t oEE = (size_t)l * EE * EE;
        const size_t oEF = (size_t)l * EE * 4 * EE;
        transpose_layer_core(wq + oEE, wk + oEE, wv + oEE, wo + oEE,
                             w1 + oEF, w2 + oEF,
                             wt + (size_t)l * WT_LAYER, r);
    } else {
        const int r = t - L_LAYERS * 6912;       // 0..23999; head 768x32000
        transpose_tile(head_w, wt + WT_HEAD_OFF, 768, 32000, r / 1000, r % 1000);
    }
}

// ---------------------------------------------------------------------------
// bf16 MFMA GEMM (128-wide tiles): C = A @ Bt^T (+bias)(+res)(+relu)
// m97-style 2-barrier loop, r4-proven config (M-fast grid, NO xcd swizzle —
// measured: swizzle tripled FETCH_SIZE on the head GEMM, r8).
// Head path (RES=0, OUTBF=0) uses non-temporal stores (config B, best total).
// ---------------------------------------------------------------------------
template<int RELU, int RES, int OUTBF, int MFRAG>
__global__ __launch_bounds__(256) void gemm_bf16(
    const u16* __restrict__ A, const u16* __restrict__ Bt,
    const float* __restrict__ bias, const float* __restrict__ res,
    void* __restrict__ Cv, int M, int N, int K)
{
    constexpr int TM = MFRAG * 32;
    __shared__ u16 As[TM * 64];
    __shared__ u16 Bs[128 * 64];

    const int tid  = threadIdx.x;
    const int lane = tid & 63;
    const int w    = tid >> 6;
    const int wr   = w >> 1, wc = w & 1;
    const int m0 = blockIdx.x * TM;     // M is the fast grid dim
    const int n0 = blockIdx.y * 128;

    const int cs = (lane & 7) ^ (lane >> 3);
    const int rl = lane >> 3;

    int aoff[2 * MFRAG], boff[8];
    const int kq = lane >> 4;
    #pragma unroll
    for (int mi = 0; mi < MFRAG; mi++) {
        int rg = wr * (MFRAG * 16) + mi * 16 + (lane & 15);
        #pragma unroll
        for (int ks = 0; ks < 2; ks++)
            aoff[2 * mi + ks] = rg * 64 + (((ks * 4 + kq) ^ (rg & 7)) * 8);
    }
    #pragma unroll
    for (int ni = 0; ni < 4; ni++) {
        int rg = wc * 64 + ni * 16 + (lane & 15);
        #pragma unroll
        for (int ks = 0; ks < 2; ks++)
            boff[2 * ni + ks] = rg * 64 + (((ks * 4 + kq) ^ (rg & 7)) * 8);
    }

    f32x4 acc[MFRAG][4] = {};

    for (int k0 = 0; k0 < K; k0 += 64) {
        __syncthreads();
        #pragma unroll
        for (int i = 0; i < MFRAG; i++) {
            const int seg = i * 4 + w;
            const int row = seg * 8 + rl;
            gload16(A + (size_t)(m0 + row) * K + k0 + cs * 8, &As[seg * 512]);
        }
        #pragma unroll
        for (int i = 0; i < 4; i++) {
            const int seg = i * 4 + w;
            const int row = seg * 8 + rl;
            gload16(Bt + (size_t)(n0 + row) * K + k0 + cs * 8, &Bs[seg * 512]);
        }
        __syncthreads();
        #pragma unroll
        for (int ks = 0; ks < 2; ks++) {
            short8 af[MFRAG], bfv[4];
            #pragma unroll
            for (int mi = 0; mi < MFRAG; mi++) af[mi] = *(const short8*)&As[aoff[2 * mi + ks]];
            #pragma unroll
            for (int ni = 0; ni < 4; ni++) bfv[ni] = *(const short8*)&Bs[boff[2 * ni + ks]];
            #pragma unroll
            for (int mi = 0; mi < MFRAG; mi++)
                #pragma unroll
                for (int ni = 0; ni < 4; ni++)
                    acc[mi][ni] = __builtin_amdgcn_mfma_f32_16x16x32_bf16(
                        af[mi], bfv[ni], acc[mi][ni], 0, 0, 0);
        }
    }

    const int rbase = m0 + wr * (MFRAG * 16) + (lane >> 4) * 4;
    const int cbase = n0 + wc * 64 + (lane & 15);
    #pragma unroll
    for (int ni = 0; ni < 4; ni++) {
        const int c = cbase + ni * 16;
        const float bv = bias ? bias[c] : 0.0f;
        #pragma unroll
        for (int mi = 0; mi < MFRAG; mi++) {
            const int r = rbase + mi * 16;
            #pragma unroll
            for (int i = 0; i < 4; i++) {
                float v = acc[mi][ni][i] + bv;
                const size_t off = (size_t)(r + i) * N + c;
                if (RES)  v += res[off];
                if (RELU) v = fmaxf(v, 0.0f);
                if (OUTBF) {
                    ((u16*)Cv)[off] = f2b(v);
                } else if (!RES) {
                    __builtin_nontemporal_store(v, &((float*)Cv)[off]);  // head
                } else {
                    ((float*)Cv)[off] = v;
                }
            }
        }
    }
}

// ---------------------------------------------------------------------------
// MFMA flash attention v4 (measured best): block per (q-tile 64, h, b),
// 256 threads = 4 waves. K dbuf via global_load_lds + XOR swizzle; V->regs
// during QK^T, LDS-written after PV. One barrier/tile. Defer-max + exp2.
// l computed by PV MFMA via ones-column in V^T rows 64..79.
// ---------------------------------------------------------------------------
#define AST 72
__global__ __launch_bounds__(256) void attn_mfma(
    const u16* __restrict__ qkv, u16* __restrict__ O)
{
    const int tid = threadIdx.x;
    const int qi = blockIdx.x;
    const int h  = blockIdx.y;
    const int b  = blockIdx.z;
    const int q0 = qi * 64;

    __shared__ u16 Ks[2][64 * 64];     // swizzled, b128-aligned rows
    __shared__ u16 Vt[2][80 * AST];    // V^T [d][k]; rows 64..79 = ones/zeros
    __shared__ u16 Ps[64 * AST];       // Q staging, then P tile (wave-private rows)

    const int lane = tid & 63;
    const int w    = tid >> 6;
    const int lr   = lane & 15;
    const int lk   = lane >> 4;        // k-group 0..3

    const int cs = (lane & 7) ^ (lane >> 3);
    const int rl = lane >> 3;
    const int vk2 = tid & 31;          // k-pair index
    const int vdc = tid >> 5;          // d-chunk 0..7

    // ---- init ones/zero rows of Vt (once) ----
    for (int i = tid; i < 16 * AST; i += 256) {
        const int r = i / AST, c = i % AST;
        const u16 v = (r == 0) ? (u16)0x3F80 : (u16)0;   // bf16 1.0
        Vt[0][(64 + r) * AST + c] = v;
        Vt[1][(64 + r) * AST + c] = v;
    }

    // ---- stage Q into Ps, hoist A-fragments ----
    {
        const int sr = tid >> 2, sc = tid & 3;
        const u16* src = qkv + (size_t)(b * TT + q0 + sr) * 2304 + h * 64 + sc * 16;
        *(ushort8v*)&Ps[sr * AST + sc * 16]     = *(const ushort8v*)src;
        *(ushort8v*)&Ps[sr * AST + sc * 16 + 8] = *(const ushort8v*)(src + 8);
    }
    __syncthreads();
    short8 aq[2];
    #pragma unroll
    for (int ks = 0; ks < 2; ks++)
        aq[ks] = *(const short8*)&Ps[(w * 16 + lr) * AST + lk * 8 + ks * 32];

    ushort8v vr0, vr1;
    auto K_ISSUE = [&](int t, int bf) {
        const int k0 = t * 64;
        #pragma unroll
        for (int j = 0; j < 2; ++j) {
            const int seg = j * 4 + w;
            const int row = seg * 8 + rl;
            gload16(qkv + (size_t)(b * TT + k0 + row) * 2304 + 768 + h * 64 + cs * 8,
                    &Ks[bf][seg * 512]);
        }
    };
    auto V_LOAD = [&](int t) {
        const int k0 = t * 64;
        const u16* p = qkv + (size_t)(b * TT + k0 + 2 * vk2) * 2304 + 1536 + h * 64 + vdc * 8;
        vr0 = *(const ushort8v*)p;
        vr1 = *(const ushort8v*)(p + 2304);
    };
    auto V_WRITE = [&](int bf) {
        #pragma unroll
        for (int j = 0; j < 8; ++j) {
            const u32 val = (u32)vr0[j] | ((u32)vr1[j] << 16);
            *(u32*)&Vt[bf][(vdc * 8 + j) * AST + 2 * vk2] = val;
        }
    };

    K_ISSUE(0, 0);
    V_LOAD(0);
    V_WRITE(0);
    __syncthreads();

    f32x4 oacc[5] = {};                // [0..3] = O d-tiles, [4] = l (ones col)
    float m_run[4];
    #pragma unroll
    for (int i = 0; i < 4; i++) m_run[i] = -3.0e38f;

    const int qrow = q0 + w * 16 + lk * 4;
    const float SC = 0.18033688f;       // 0.125 * log2(e): scores in log2 domain

    for (int t = 0; t <= qi; ++t) {
        const int cur = t & 1;

        // ---- QK^T ----
        f32x4 sfrag[4] = {};
        #pragma unroll
        for (int ks = 0; ks < 2; ks++)
            #pragma unroll
            for (int nt = 0; nt < 4; nt++) {
                const int rg = nt * 16 + lr;
                short8 bk = *(const short8*)&Ks[cur][rg * 64 + (((ks * 4 + lk) ^ (rg & 7)) * 8)];
                sfrag[nt] = __builtin_amdgcn_mfma_f32_16x16x32_bf16(aq[ks], bk, sfrag[nt], 0, 0, 0);
            }

        // ---- prefetch next tile (K -> LDS dbuf, V -> regs) ----
        if (t < qi) { K_ISSUE(t + 1, cur ^ 1); V_LOAD(t + 1); }

        // ---- softmax in log2 domain (defer-max; l via MFMA ones-column) ----
        const int k0 = t * 64;
        float sv[4][4], mxv[4];
        float need = 0.0f;
        #pragma unroll
        for (int i = 0; i < 4; i++) {
            float mx = -3.0e38f;
            #pragma unroll
            for (int nt = 0; nt < 4; nt++) {
                float s = sfrag[nt][i] * SC;
                if (t == qi && (k0 + nt * 16 + lr) > (qrow + i)) s = -3.0e38f;
                sv[i][nt] = s;
                mx = fmaxf(mx, s);
            }
            mx = fmaxf(mx, __shfl_xor(mx, 1));
            mx = fmaxf(mx, __shfl_xor(mx, 2));
            mx = fmaxf(mx, __shfl_xor(mx, 4));
            mx = fmaxf(mx, __shfl_xor(mx, 8));
            mxv[i] = mx;
            need = fmaxf(need, mx - m_run[i]);
        }
        if (!__all(need <= 11.5f)) {       // = 8 nats in log2 units
            #pragma unroll
            for (int i = 0; i < 4; i++) {
                const float m_new = fmaxf(m_run[i], mxv[i]);
                const float scale = exp2f(m_run[i] - m_new);
                #pragma unroll
                for (int dt = 0; dt < 5; dt++) oacc[dt][i] *= scale;
                m_run[i] = m_new;
            }
        }
        #pragma unroll
        for (int i = 0; i < 4; i++)
            #pragma unroll
            for (int nt = 0; nt < 4; nt++)
                sv[i][nt] = exp2f(sv[i][nt] - m_run[i]);

        // ---- P (bf16) to LDS — wave-private rows, no barrier needed ----
        #pragma unroll
        for (int i = 0; i < 4; i++)
            #pragma unroll
            for (int nt = 0; nt < 4; nt++)
                Ps[(w * 16 + lk * 4 + i) * AST + nt * 16 + lr] = f2b(sv[i][nt]);

        // ---- PV (+ l via dt=4 ones-column) ----
        #pragma unroll
        for (int ks = 0; ks < 2; ks++) {
            short8 ap = *(const short8*)&Ps[(w * 16 + lr) * AST + lk * 8 + ks * 32];
            #pragma unroll
            for (int dt = 0; dt < 5; dt++) {
                short8 bv = *(const short8*)&Vt[cur][(dt * 16 + lr) * AST + lk * 8 + ks * 32];
                oacc[dt] = __builtin_amdgcn_mfma_f32_16x16x32_bf16(ap, bv, oacc[dt], 0, 0, 0);
            }
        }

        if (t < qi) V_WRITE(cur ^ 1);
        __syncthreads();
    }

    // ---- epilogue: l lives in lanes lr==0 of oacc[4]; broadcast per group ----
    #pragma unroll
    for (int i = 0; i < 4; i++) {
        const float li  = __shfl(oacc[4][i], lane & 48);
        const float inv = 1.0f / li;
        u16* dst = O + (size_t)(b * TT + q0 + w * 16 + lk * 4 + i) * 768 + h * 64 + lr;
        #pragma unroll
        for (int dt = 0; dt < 4; dt++)
            dst[dt * 16] = f2b(oacc[dt][i] * inv);
    }
}

// ---------------------------------------------------------------------------
// Host-side launch
// ---------------------------------------------------------------------------
extern "C" void kernel_launch(void* const* d_in, const int* in_sizes, int n_in,
                              void* d_out, int out_size, void* d_ws, size_t ws_size,
                              hipStream_t stream)
{
    (void)in_sizes; (void)n_in; (void)out_size;

    const int*   idx     = (const int*)  d_in[0];
    const float* tok_emb = (const float*)d_in[1];
    const float* pos_emb = (const float*)d_in[2];
    const float* ln1_w   = (const float*)d_in[3];
    const float* ln1_b   = (const float*)d_in[4];
    const float* wq      = (const float*)d_in[5];
    const float* wk      = (const float*)d_in[6];
    const float* wv      = (const float*)d_in[7];
    const float* wo      = (const float*)d_in[8];
    const float* bo      = (const float*)d_in[9];
    const float* ln2_w   = (const float*)d_in[10];
    const float* ln2_b   = (const float*)d_in[11];
    const float* w1      = (const float*)d_in[12];
    const float* b1      = (const float*)d_in[13];
    const float* w2      = (const float*)d_in[14];
    const float* b2      = (const float*)d_in[15];
    const float* lnf_w   = (const float*)d_in[16];
    const float* lnf_b   = (const float*)d_in[17];
    const float* head_w  = (const float*)d_in[18];
    const float* head_b  = (const float*)d_in[19];
    float* out = (float*)d_out;

    // workspace carve
    const size_t S = (size_t)BT * EE;                 // 3,145,728
    float* x   = (float*)d_ws;                        // f32 [BT,768]
    u16*  qkv  = (u16*)(x + S);                       // bf16 [BT,2304]
    u16*  hb   = qkv + (size_t)BT * 2304;             // bf16 [BT,768]
    u16*  ffh  = hb + S;                              // bf16 [BT,3072]
    u16*  wt   = ffh + (size_t)BT * 3072;             // bf16 weights

    // big path needs 62.9 MB activations + 134.1 MB all-layer weights
    const size_t need_big = 62914560u + 134086656u + 1024;
    const bool big = (ws_size >= need_big);

    embed_kernel<<<BT * EE / 256, 256, 0, stream>>>(idx, tok_emb, pos_emb, x);

    if (big)   // all transposes (6 layers + head) in one dispatch
        transpose_all<<<L_LAYERS * 6912 + 24000, 256, 0, stream>>>(
            wq, wk, wv, wo, w1, w2, head_w, wt);

    for (int l = 0; l < L_LAYERS; l++) {
        const size_t oE  = (size_t)l * EE;
        const size_t oEE = (size_t)l * EE * EE;
        const size_t oEF = (size_t)l * EE * 4 * EE;
        u16* wtl = big ? (wt + (size_t)l * WT_LAYER) : wt;

        if (!big)
            transpose_layer<<<6912, 256, 0, stream>>>(
                wq + oEE, wk + oEE, wv + oEE, wo + oEE, w1 + oEF, w2 + oEF, wtl);

        // h = LN1(x)
        ln_kernel<<<BT / 4, 256, 0, stream>>>(x, ln1_w + oE, ln1_b + oE, hb);
        // qkv = h @ [Wq|Wk|Wv]   (bf16 out)
        gemm_bf16<0, 0, 1, 4><<<dim3(BT / 128, 2304 / 128), 256, 0, stream>>>(
            hb, wtl, nullptr, nullptr, qkv, BT, 2304, 768);
        // h = attention(qkv)  — MFMA flash v4
        attn_mfma<<<dim3(TT / 64, HH, BB), 256, 0, stream>>>(qkv, hb);
        // x = x + h @ Wo + bo   (TM=64: 384 blocks)
        gemm_bf16<0, 1, 0, 2><<<dim3(BT / 64, 768 / 128), 256, 0, stream>>>(
            hb, wtl + (size_t)3 * 768 * 768, bo + oE, x, x, BT, 768, 768);
        // h = LN2(x)
        ln_kernel<<<BT / 4, 256, 0, stream>>>(x, ln2_w + oE, ln2_b + oE, hb);
        // ffh = relu(h @ W1 + b1)  (bf16 out)
        gemm_bf16<1, 0, 1, 4><<<dim3(BT / 128, 3072 / 128), 256, 0, stream>>>(
            hb, wtl + (size_t)4 * 768 * 768, b1 + (size_t)l * 4 * EE, nullptr, ffh, BT, 3072, 768);
        // x = x + ffh @ W2 + b2   (TM=64: 384 blocks)
        gemm_bf16<0, 1, 0, 2><<<dim3(BT / 64, 768 / 128), 256, 0, stream>>>(
            ffh, wtl + (size_t)4 * 768 * 768 + (size_t)3072 * 768, b2 + oE, x, x, BT, 768, 3072);
    }

    // final LN + head (non-temporal f32 stores)
    ln_kernel<<<BT / 4, 256, 0, stream>>>(x, lnf_w, lnf_b, hb);
    u16* wth = big ? (wt + WT_HEAD_OFF) : wt;
    if (!big)
        transpose_cvt<<<dim3(VV / 32, EE / 32), 256, 0, stream>>>(head_w, wth, EE, VV);
    gemm_bf16<0, 0, 0, 4><<<dim3(BT / 128, VV / 128), 256, 0, stream>>>(
        hb, wth, head_b, nullptr, out, BT, VV, 768);
}